// Round 7
// baseline (331.042 us; speedup 1.0000x reference)
//
#include <hip/hip_runtime.h>
#include <hip/hip_bf16.h>

#define N_NODES 100000
#define N_EDGES 1600000
#define IN_FEA 128
#define HIDDEN 128
#define RANK 64

#define NBUCK 391          // ceil(N_NODES/256): bucket b = nodes [b*256, b*256+256)
#define C_BLOCKS 1024      // hist blocks
#define EPB 1563           // edges per hist block
#define S_BLOCKS 128       // binscatter blocks (chunk = 8 hist rows)
#define CHUNK_W (EPB * 8)  // 12504 edges per scatter chunk
#define GEMM1_BLOCKS 1563  // ceil(N_NODES / 64)

#define AGG_BLOCKS 6250    // N_NODES / 16: one node per wave (R9 proven shape)
#define G2_BLOCKS 6250     // gemm2: 6250 x 4 waves x 4 nodes = 100000 exactly
#define G2_NPW 4

// ---------------- helpers ----------------

__device__ __forceinline__ void fma4(float4& a, float s, const float4& b) {
    a.x = fmaf(s, b.x, a.x);
    a.y = fmaf(s, b.y, a.y);
    a.z = fmaf(s, b.z, a.z);
    a.w = fmaf(s, b.w, a.w);
}

__device__ __forceinline__ unsigned short f2bf_rne(float f) {
    unsigned u = __float_as_uint(f);
    u += 0x7fffu + ((u >> 16) & 1u);
    return (unsigned short)(u >> 16);
}

// low bf16 of a packed uint -> float (1 VALU: lshl)
__device__ __forceinline__ float bfu_lo(unsigned u) {
    return __uint_as_float(u << 16);
}
// high bf16 of a packed uint -> float (1 VALU: and)
__device__ __forceinline__ float bfu_hi(unsigned u) {
    return __uint_as_float(u & 0xffff0000u);
}

// ---------------- fused GEMM1 + bucket histogram ----------------
// blocks [0, GEMM1_BLOCKS): h_bf = bf16(x @ W), 64 nodes/block.
// blocks [GEMM1_BLOCKS, +C_BLOCKS): per-block bucket histogram (EPB edges each).

__global__ __launch_bounds__(256) void gemm1_hist_kernel(const float* __restrict__ x,
                                                         const float* __restrict__ W,
                                                         unsigned short* __restrict__ hb,
                                                         const int* __restrict__ dst,
                                                         int* __restrict__ bhist,
                                                         int* __restrict__ blockhist) {
    __shared__ float Wl[IN_FEA * RANK];  // 32 KB (hist aliases first 1.6 KB)
    int t = threadIdx.x;

    if (blockIdx.x >= GEMM1_BLOCKS) {
        int* hist = (int*)Wl;
        int b = blockIdx.x - GEMM1_BLOCKS;
        for (int i = t; i < NBUCK; i += 256) hist[i] = 0;
        __syncthreads();
        int b0 = b * EPB;
        int b1 = min(b0 + EPB, N_EDGES);
        for (int e = b0 + t; e < b1; e += 256)
            atomicAdd(&hist[dst[e] >> 8], 1);
        __syncthreads();
        for (int i = t; i < NBUCK; i += 256) {
            int c = hist[i];
            blockhist[b * NBUCK + i] = c;
            if (c) atomicAdd(&bhist[i], c);
        }
        return;
    }

    for (int i = t; i < IN_FEA * RANK; i += 256) Wl[i] = W[i];
    __syncthreads();

    int r0 = (t & 15) * 4;
    int n0 = blockIdx.x * 64 + (t >> 4) * 4;
    const float4* x0 = (const float4*)(x + (long)min(n0 + 0, N_NODES - 1) * IN_FEA);
    const float4* x1 = (const float4*)(x + (long)min(n0 + 1, N_NODES - 1) * IN_FEA);
    const float4* x2 = (const float4*)(x + (long)min(n0 + 2, N_NODES - 1) * IN_FEA);
    const float4* x3 = (const float4*)(x + (long)min(n0 + 3, N_NODES - 1) * IN_FEA);
    float4 a0 = {0.f, 0.f, 0.f, 0.f}, a1 = a0, a2 = a0, a3 = a0;
    for (int k4 = 0; k4 < IN_FEA / 4; ++k4) {
        float4 v0 = x0[k4], v1 = x1[k4], v2 = x2[k4], v3 = x3[k4];
        int kb = k4 * 4;
        float4 w0 = *(const float4*)&Wl[(kb + 0) * RANK + r0];
        float4 w1 = *(const float4*)&Wl[(kb + 1) * RANK + r0];
        float4 w2 = *(const float4*)&Wl[(kb + 2) * RANK + r0];
        float4 w3 = *(const float4*)&Wl[(kb + 3) * RANK + r0];
        fma4(a0, v0.x, w0); fma4(a0, v0.y, w1); fma4(a0, v0.z, w2); fma4(a0, v0.w, w3);
        fma4(a1, v1.x, w0); fma4(a1, v1.y, w1); fma4(a1, v1.z, w2); fma4(a1, v1.w, w3);
        fma4(a2, v2.x, w0); fma4(a2, v2.y, w1); fma4(a2, v2.z, w2); fma4(a2, v2.w, w3);
        fma4(a3, v3.x, w0); fma4(a3, v3.y, w1); fma4(a3, v3.z, w2); fma4(a3, v3.w, w3);
    }
    float4 accs[4] = {a0, a1, a2, a3};
#pragma unroll
    for (int i = 0; i < 4; ++i) {
        if (n0 + i < N_NODES) {
            ushort4 o;
            o.x = f2bf_rne(accs[i].x); o.y = f2bf_rne(accs[i].y);
            o.z = f2bf_rne(accs[i].z); o.w = f2bf_rne(accs[i].w);
            *(ushort4*)(hb + (n0 + i) * RANK + r0) = o;
        }
    }
}

// ---------------- CSR build (rest) ----------------

__global__ void bucket_scan_kernel(const int* __restrict__ bhist,
                                   int* __restrict__ bucket_offs,
                                   int* __restrict__ bucket_cursor,
                                   int* __restrict__ offs) {
    __shared__ int sd[512];
    int t = threadIdx.x;
    int v = (t < NBUCK) ? bhist[t] : 0;
    sd[t] = v;
    __syncthreads();
    for (int off = 1; off < 512; off <<= 1) {
        int a = 0;
        if (t >= off) a = sd[t - off];
        __syncthreads();
        sd[t] += a;
        __syncthreads();
    }
    if (t < NBUCK) {
        int excl = sd[t] - v;
        bucket_offs[t] = excl;
        bucket_cursor[t] = excl;
    }
    if (t == 0) {
        bucket_offs[NBUCK] = N_EDGES;
        offs[N_NODES] = N_EDGES;
    }
}

// Fat-chunk scatter: 128 blocks x 1024 threads, one read pass. Per (block,bucket)
// run length ~= 12504/391 ~= 32 edges = 128 B -> mostly full-line writebacks
// (kills the partial-line write amplification + RFO fetches of the 1024-block form).
__global__ __launch_bounds__(1024) void binscatter_kernel(const int* __restrict__ src,
                                                          const int* __restrict__ dst,
                                                          const int* __restrict__ blockhist,
                                                          int* __restrict__ bucket_cursor,
                                                          unsigned* __restrict__ pairs) {
    __shared__ int wbase[NBUCK];
    __shared__ int cur[NBUCK];
    int t = threadIdx.x;
    int b = blockIdx.x;
    if (t < NBUCK) {
        int s = 0;
#pragma unroll
        for (int k = 0; k < 8; ++k)
            s += blockhist[(8 * b + k) * NBUCK + t];
        wbase[t] = s ? atomicAdd(&bucket_cursor[t], s) : 0;
        cur[t] = 0;
    }
    __syncthreads();
    int e0 = b * CHUNK_W;
    int e1 = min(e0 + CHUNK_W, N_EDGES);
    for (int e = e0 + t; e < e1; e += 1024) {
        int d = dst[e];
        int s = src[e];
        int bk = d >> 8;
        int lp = atomicAdd(&cur[bk], 1);
        pairs[wbase[bk] + lp] = ((unsigned)s << 8) | (unsigned)(d & 255);
    }
}

__global__ __launch_bounds__(256) void bucket_build_kernel(const unsigned* __restrict__ pairs,
                                                           const int* __restrict__ bucket_offs,
                                                           int* __restrict__ offs,
                                                           int* __restrict__ eidx) {
    __shared__ int dcnt[256];
    __shared__ int sd[256];
    __shared__ int cur[256];
    int b = blockIdx.x, t = threadIdx.x;
    int base = bucket_offs[b], end = bucket_offs[b + 1];
    dcnt[t] = 0;
    __syncthreads();
    for (int i = base + t; i < end; i += 256)
        atomicAdd(&dcnt[pairs[i] & 255u], 1);
    __syncthreads();
    int v = dcnt[t];
    sd[t] = v;
    __syncthreads();
    for (int off = 1; off < 256; off <<= 1) {
        int a = 0;
        if (t >= off) a = sd[t - off];
        __syncthreads();
        sd[t] += a;
        __syncthreads();
    }
    int excl = sd[t] - v;
    int node = b * 256 + t;
    if (node < N_NODES) offs[node] = base + excl;
    cur[t] = excl;
    __syncthreads();
    for (int i = base + t; i < end; i += 256) {
        unsigned r = pairs[i];
        int lp = atomicAdd(&cur[r & 255u], 1);
        eidx[base + lp] = (int)(r >> 8);
    }
}

// ---------------- aggregation (gather + product only) ----------------
// R14 de-fuse kept: fused epilogues force one register/occupancy config onto
// two phases with opposite needs. p staged into out[n][0:64] (gemm2 reads it
// and overwrites the same row in-place, same wave -> no race).
// This kernel: R9/R11 proven gather shape (1 node/wave, 16 waves, 6250 blocks,
// short-lived blocks retire in dispatch order -> L2-warm hb gathers), ZERO LDS,
// ~28 VGPR -> wave-slot-capped occupancy, max gather latency hiding.

__global__ __launch_bounds__(1024) void agg_kernel(const unsigned short* __restrict__ hb,
                                                   const float* __restrict__ norm,
                                                   const int* __restrict__ offs,
                                                   const int* __restrict__ eidx,
                                                   float* __restrict__ out) {
    int t = threadIdx.x;
    int wave = t >> 6, lane = t & 63;
    int half = lane >> 5;      // which edge of the pair this lane serves
    int l32 = lane & 31;       // rank-pair index: ranks {2*l32, 2*l32+1}
    int node = blockIdx.x * 16 + wave;
    int beg = offs[node], end = offs[node + 1];
    const unsigned* hb2 = (const unsigned*)hb;  // hb2[s*32 + l32] = packed ranks {2*l32, 2*l32+1}

    float plo = 1.0f, phi = 1.0f;
    for (int c = beg; c < end; c += 64) {
        int n = min(64, end - c);
        int sidx = (c + lane < end) ? eidx[c + lane] : 0;
        int j = 0;
        // 8 loads in flight = 16 edges
        for (; j + 16 <= n; j += 16) {
            int s0 = __shfl(sidx, j + 0  + half);
            int s1 = __shfl(sidx, j + 2  + half);
            int s2 = __shfl(sidx, j + 4  + half);
            int s3 = __shfl(sidx, j + 6  + half);
            int s4 = __shfl(sidx, j + 8  + half);
            int s5 = __shfl(sidx, j + 10 + half);
            int s6 = __shfl(sidx, j + 12 + half);
            int s7 = __shfl(sidx, j + 14 + half);
            unsigned u0 = hb2[(s0 << 5) | l32];
            unsigned u1 = hb2[(s1 << 5) | l32];
            unsigned u2 = hb2[(s2 << 5) | l32];
            unsigned u3 = hb2[(s3 << 5) | l32];
            unsigned u4 = hb2[(s4 << 5) | l32];
            unsigned u5 = hb2[(s5 << 5) | l32];
            unsigned u6 = hb2[(s6 << 5) | l32];
            unsigned u7 = hb2[(s7 << 5) | l32];
            plo *= ((bfu_lo(u0) * bfu_lo(u1)) * (bfu_lo(u2) * bfu_lo(u3))) *
                   ((bfu_lo(u4) * bfu_lo(u5)) * (bfu_lo(u6) * bfu_lo(u7)));
            phi *= ((bfu_hi(u0) * bfu_hi(u1)) * (bfu_hi(u2) * bfu_hi(u3))) *
                   ((bfu_hi(u4) * bfu_hi(u5)) * (bfu_hi(u6) * bfu_hi(u7)));
        }
        // 4 loads = 8 edges
        for (; j + 8 <= n; j += 8) {
            int s0 = __shfl(sidx, j + 0 + half);
            int s1 = __shfl(sidx, j + 2 + half);
            int s2 = __shfl(sidx, j + 4 + half);
            int s3 = __shfl(sidx, j + 6 + half);
            unsigned u0 = hb2[(s0 << 5) | l32];
            unsigned u1 = hb2[(s1 << 5) | l32];
            unsigned u2 = hb2[(s2 << 5) | l32];
            unsigned u3 = hb2[(s3 << 5) | l32];
            plo *= (bfu_lo(u0) * bfu_lo(u1)) * (bfu_lo(u2) * bfu_lo(u3));
            phi *= (bfu_hi(u0) * bfu_hi(u1)) * (bfu_hi(u2) * bfu_hi(u3));
        }
        // pair tail (2 edges / iter; odd edge masked to identity on upper half)
        for (; j < n; j += 2) {
            int jj = j + half;                 // jj <= n <= 64; lane n has sidx=0 -> safe addr
            int s = __shfl(sidx, jj);
            unsigned u = hb2[(s << 5) | l32];
            float alo = bfu_lo(u), ahi = bfu_hi(u);
            if (jj >= n) { alo = 1.0f; ahi = 1.0f; }
            plo *= alo;
            phi *= ahi;
        }
    }
    // merge edge-parity halves: lane l and lane l^32 hold the same rank pair
    plo *= __shfl_xor(plo, 32);
    phi *= __shfl_xor(phi, 32);

    if (lane < 32) {
        float nrm = norm[node];
        float2 o;
        o.x = plo * nrm;
        o.y = phi * nrm;
        // p[node] staged into out[node][0:64] (two full 128 B lines)
        *(float2*)&out[(long)node * HIDDEN + l32 * 2] = o;
    }
}

// ---------------- GEMM2 (in-place: out[n][0:64] = p -> out[n][0:128]) ----------------
// R15 post-mortem of R14's 75.7 us: (a) VGPR pinned at 84 < the 128 needed for
// V-in-regs -> compiler sank V loads into the loop (~800 MB L1/L2 traffic);
// (b) "uniform -> s_load" was illegal for an in-place buffer (out is written by
// this kernel; scalar cache not coherent) -> uniform-address VECTOR loads on a
// 5000-wave grid = latency-bound at 26% VALUBusy.
// Fix: v_readlane broadcast. Lane l loads p[node][l] (coalesced 256 B);
// readlane(pl, r) with literal r puts p[r] in an SGPR (1 instr) feeding two
// v_fmac with SGPR operand. Zero LDS, zero DS traffic, zero per-r memory ops.
// 4 nodes/wave x 25000 waves (5x R14) interleaved in one r-loop (12 VALU/r).
// __launch_bounds__(256,1) releases the occupancy clamp so the 128-VGPR V set
// stays resident (~150 VGPR -> 3 waves/SIMD, 24 wave-generations of work).
// VALU floor: 768 instr/wave x 24.4 waves/SIMD x 2 cyc ~= 15.6 us.
// In-place safety: wave reads p only from rows it alone later writes.

__global__ __launch_bounds__(256, 1) void gemm2_kernel(const float* __restrict__ V,
                                                       float* __restrict__ out) {
    int t = threadIdx.x, w = t >> 6, lane = t & 63;

    // V rows for this lane's two output columns (h = lane, h = lane+64)
    float4 va[16], vb[16];
    const float4* Va = (const float4*)(V + lane * RANK);
    const float4* Vb = (const float4*)(V + (lane + 64) * RANK);
#pragma unroll
    for (int q = 0; q < 16; ++q) { va[q] = Va[q]; vb[q] = Vb[q]; }
    const float* vaf = (const float*)va;
    const float* vbf = (const float*)vb;

    int n0 = (blockIdx.x * 4 + w) * G2_NPW;

    // read all 4 p rows first (reads precede this wave's writes; 4 loads in flight)
    float pl0 = out[(long)(n0 + 0) * HIDDEN + lane];
    float pl1 = out[(long)(n0 + 1) * HIDDEN + lane];
    float pl2 = out[(long)(n0 + 2) * HIDDEN + lane];
    float pl3 = out[(long)(n0 + 3) * HIDDEN + lane];

    float a00 = 0.f, a01 = 0.f, a10 = 0.f, a11 = 0.f;
    float a20 = 0.f, a21 = 0.f, a30 = 0.f, a31 = 0.f;
#pragma unroll
    for (int r = 0; r < 64; ++r) {
        float vA = vaf[r];          // constant index -> stays in VGPR
        float vB = vbf[r];
        float p0 = __uint_as_float(__builtin_amdgcn_readlane(__float_as_uint(pl0), r));
        float p1 = __uint_as_float(__builtin_amdgcn_readlane(__float_as_uint(pl1), r));
        float p2 = __uint_as_float(__builtin_amdgcn_readlane(__float_as_uint(pl2), r));
        float p3 = __uint_as_float(__builtin_amdgcn_readlane(__float_as_uint(pl3), r));
        a00 = fmaf(p0, vA, a00);
        a01 = fmaf(p0, vB, a01);
        a10 = fmaf(p1, vA, a10);
        a11 = fmaf(p1, vB, a11);
        a20 = fmaf(p2, vA, a20);
        a21 = fmaf(p2, vB, a21);
        a30 = fmaf(p3, vA, a30);
        a31 = fmaf(p3, vB, a31);
    }

    out[(long)(n0 + 0) * HIDDEN + lane]      = a00;
    out[(long)(n0 + 0) * HIDDEN + 64 + lane] = a01;
    out[(long)(n0 + 1) * HIDDEN + lane]      = a10;
    out[(long)(n0 + 1) * HIDDEN + 64 + lane] = a11;
    out[(long)(n0 + 2) * HIDDEN + lane]      = a20;
    out[(long)(n0 + 2) * HIDDEN + 64 + lane] = a21;
    out[(long)(n0 + 3) * HIDDEN + lane]      = a30;
    out[(long)(n0 + 3) * HIDDEN + 64 + lane] = a31;
}

// ---------------- launch ----------------

extern "C" void kernel_launch(void* const* d_in, const int* in_sizes, int n_in,
                              void* d_out, int out_size, void* d_ws, size_t ws_size,
                              hipStream_t stream) {
    const float* x    = (const float*)d_in[0];
    const float* norm = (const float*)d_in[1];
    const float* W    = (const float*)d_in[2];
    const float* V    = (const float*)d_in[3];
    const int*   src  = (const int*)d_in[4];
    const int*   dst  = (const int*)d_in[5];
    float* out = (float*)d_out;

    // workspace layout (ws): hb (bf16), offs, eidx, small bucket arrays
    unsigned short* hb = (unsigned short*)d_ws;              // N*RANK bf16 (12.8 MB)
    int*   offs        = (int*)(hb + (long)N_NODES * RANK);  // N+1
    int*   eidx        = offs + N_NODES + 1;                 // E
    int*   bhist       = eidx + N_EDGES;                     // NBUCK
    int*   bucket_offs = bhist + NBUCK;                      // NBUCK+1
    int*   bucket_cur  = bucket_offs + NBUCK + 1;            // NBUCK

    // scratch inside d_out (dead once consumed; agg/gemm2 then own the rows):
    unsigned* pairs    = (unsigned*)d_out;                   // E uint32 (6.4 MB)
    int*     blockhist = (int*)d_out + 2097152;              // at +8 MB: C_BLOCKS*NBUCK ints (1.6 MB)

    hipMemsetAsync(bhist, 0, NBUCK * sizeof(int), stream);
    gemm1_hist_kernel<<<GEMM1_BLOCKS + C_BLOCKS, 256, 0, stream>>>(x, W, hb, dst, bhist, blockhist);
    bucket_scan_kernel<<<1, 512, 0, stream>>>(bhist, bucket_offs, bucket_cur, offs);
    binscatter_kernel<<<S_BLOCKS, 1024, 0, stream>>>(src, dst, blockhist, bucket_cur, pairs);
    bucket_build_kernel<<<NBUCK, 256, 0, stream>>>(pairs, bucket_offs, offs, eidx);
    agg_kernel<<<AGG_BLOCKS, 1024, 0, stream>>>(hb, norm, offs, eidx, out);
    gemm2_kernel<<<G2_BLOCKS, 256, 0, stream>>>(V, out);
}

// Round 8
// 246.041 us; speedup vs baseline: 1.3455x; 1.3455x over previous
//
#include <hip/hip_runtime.h>
#include <hip/hip_bf16.h>

#define N_NODES 100000
#define N_EDGES 1600000
#define IN_FEA 128
#define HIDDEN 128
#define RANK 64

#define NBUCK 391          // ceil(N_NODES/256): bucket b = nodes [b*256, b*256+256)
#define C_BLOCKS 1024      // hist blocks
#define EPB 1563           // edges per hist block
#define S_BLOCKS 256       // binscatter blocks (chunk = 4 hist rows) -- R16: was 128 (half the GPU idle)
#define CHUNK_W (EPB * 4)  // 6252 edges per scatter chunk
#define GEMM1_BLOCKS 1563  // ceil(N_NODES / 64)

#define NPW 2              // nodes per wave in agg_gemm (V-read amortization)
#define AGG_BLOCKS 3125    // N_NODES / (16 waves * NPW) exactly

// ---------------- helpers ----------------

__device__ __forceinline__ void fma4(float4& a, float s, const float4& b) {
    a.x = fmaf(s, b.x, a.x);
    a.y = fmaf(s, b.y, a.y);
    a.z = fmaf(s, b.z, a.z);
    a.w = fmaf(s, b.w, a.w);
}

__device__ __forceinline__ unsigned short f2bf_rne(float f) {
    unsigned u = __float_as_uint(f);
    u += 0x7fffu + ((u >> 16) & 1u);
    return (unsigned short)(u >> 16);
}

// low bf16 of a packed uint -> float (1 VALU: lshl)
__device__ __forceinline__ float bfu_lo(unsigned u) {
    return __uint_as_float(u << 16);
}
// high bf16 of a packed uint -> float (1 VALU: and)
__device__ __forceinline__ float bfu_hi(unsigned u) {
    return __uint_as_float(u & 0xffff0000u);
}

// ---------------- fused GEMM1 + bucket histogram ----------------
// blocks [0, GEMM1_BLOCKS): h_bf = bf16(x @ W), 64 nodes/block.
// blocks [GEMM1_BLOCKS, +C_BLOCKS): per-block bucket histogram (EPB edges each).

__global__ __launch_bounds__(256) void gemm1_hist_kernel(const float* __restrict__ x,
                                                         const float* __restrict__ W,
                                                         unsigned short* __restrict__ hb,
                                                         const int* __restrict__ dst,
                                                         int* __restrict__ bhist,
                                                         int* __restrict__ blockhist) {
    __shared__ float Wl[IN_FEA * RANK];  // 32 KB (hist aliases first 1.6 KB)
    int t = threadIdx.x;

    if (blockIdx.x >= GEMM1_BLOCKS) {
        int* hist = (int*)Wl;
        int b = blockIdx.x - GEMM1_BLOCKS;
        for (int i = t; i < NBUCK; i += 256) hist[i] = 0;
        __syncthreads();
        int b0 = b * EPB;
        int b1 = min(b0 + EPB, N_EDGES);
        for (int e = b0 + t; e < b1; e += 256)
            atomicAdd(&hist[dst[e] >> 8], 1);
        __syncthreads();
        for (int i = t; i < NBUCK; i += 256) {
            int c = hist[i];
            blockhist[b * NBUCK + i] = c;
            if (c) atomicAdd(&bhist[i], c);
        }
        return;
    }

    for (int i = t; i < IN_FEA * RANK; i += 256) Wl[i] = W[i];
    __syncthreads();

    int r0 = (t & 15) * 4;
    int n0 = blockIdx.x * 64 + (t >> 4) * 4;
    const float4* x0 = (const float4*)(x + (long)min(n0 + 0, N_NODES - 1) * IN_FEA);
    const float4* x1 = (const float4*)(x + (long)min(n0 + 1, N_NODES - 1) * IN_FEA);
    const float4* x2 = (const float4*)(x + (long)min(n0 + 2, N_NODES - 1) * IN_FEA);
    const float4* x3 = (const float4*)(x + (long)min(n0 + 3, N_NODES - 1) * IN_FEA);
    float4 a0 = {0.f, 0.f, 0.f, 0.f}, a1 = a0, a2 = a0, a3 = a0;
    for (int k4 = 0; k4 < IN_FEA / 4; ++k4) {
        float4 v0 = x0[k4], v1 = x1[k4], v2 = x2[k4], v3 = x3[k4];
        int kb = k4 * 4;
        float4 w0 = *(const float4*)&Wl[(kb + 0) * RANK + r0];
        float4 w1 = *(const float4*)&Wl[(kb + 1) * RANK + r0];
        float4 w2 = *(const float4*)&Wl[(kb + 2) * RANK + r0];
        float4 w3 = *(const float4*)&Wl[(kb + 3) * RANK + r0];
        fma4(a0, v0.x, w0); fma4(a0, v0.y, w1); fma4(a0, v0.z, w2); fma4(a0, v0.w, w3);
        fma4(a1, v1.x, w0); fma4(a1, v1.y, w1); fma4(a1, v1.z, w2); fma4(a1, v1.w, w3);
        fma4(a2, v2.x, w0); fma4(a2, v2.y, w1); fma4(a2, v2.z, w2); fma4(a2, v2.w, w3);
        fma4(a3, v3.x, w0); fma4(a3, v3.y, w1); fma4(a3, v3.z, w2); fma4(a3, v3.w, w3);
    }
    float4 accs[4] = {a0, a1, a2, a3};
#pragma unroll
    for (int i = 0; i < 4; ++i) {
        if (n0 + i < N_NODES) {
            ushort4 o;
            o.x = f2bf_rne(accs[i].x); o.y = f2bf_rne(accs[i].y);
            o.z = f2bf_rne(accs[i].z); o.w = f2bf_rne(accs[i].w);
            *(ushort4*)(hb + (n0 + i) * RANK + r0) = o;
        }
    }
}

// ---------------- CSR build (rest) ----------------

__global__ void bucket_scan_kernel(const int* __restrict__ bhist,
                                   int* __restrict__ bucket_offs,
                                   int* __restrict__ bucket_cursor,
                                   int* __restrict__ offs) {
    __shared__ int sd[512];
    int t = threadIdx.x;
    int v = (t < NBUCK) ? bhist[t] : 0;
    sd[t] = v;
    __syncthreads();
    for (int off = 1; off < 512; off <<= 1) {
        int a = 0;
        if (t >= off) a = sd[t - off];
        __syncthreads();
        sd[t] += a;
        __syncthreads();
    }
    if (t < NBUCK) {
        int excl = sd[t] - v;
        bucket_offs[t] = excl;
        bucket_cursor[t] = excl;
    }
    if (t == 0) {
        bucket_offs[NBUCK] = N_EDGES;
        offs[N_NODES] = N_EDGES;
    }
}

// Fat-chunk scatter, now on the FULL chip: 256 blocks x 1024 threads.
// Per (block,bucket) run length ~= 6252/391 ~= 16 edges = 64 B (half-line
// writebacks on the 6.4 MB pairs array -- mild amplification, traded for 2x
// CU coverage vs the 128-block form that left half the GPU idle).
__global__ __launch_bounds__(1024) void binscatter_kernel(const int* __restrict__ src,
                                                          const int* __restrict__ dst,
                                                          const int* __restrict__ blockhist,
                                                          int* __restrict__ bucket_cursor,
                                                          unsigned* __restrict__ pairs) {
    __shared__ int wbase[NBUCK];
    __shared__ int cur[NBUCK];
    int t = threadIdx.x;
    int b = blockIdx.x;
    if (t < NBUCK) {
        int s = 0;
#pragma unroll
        for (int k = 0; k < 4; ++k)
            s += blockhist[(4 * b + k) * NBUCK + t];
        wbase[t] = s ? atomicAdd(&bucket_cursor[t], s) : 0;
        cur[t] = 0;
    }
    __syncthreads();
    int e0 = b * CHUNK_W;
    int e1 = min(e0 + CHUNK_W, N_EDGES);
    for (int e = e0 + t; e < e1; e += 1024) {
        int d = dst[e];
        int s = src[e];
        int bk = d >> 8;
        int lp = atomicAdd(&cur[bk], 1);
        pairs[wbase[bk] + lp] = ((unsigned)s << 8) | (unsigned)(d & 255);
    }
}

// R16: 1024 threads per bucket (was 256: only ~8 waves/CU = 25% wave slots).
// Edge loops stride 1024; the 256-wide count/scan phases are masked to t<256
// with all threads executing the barriers.
__global__ __launch_bounds__(1024) void bucket_build_kernel(const unsigned* __restrict__ pairs,
                                                            const int* __restrict__ bucket_offs,
                                                            int* __restrict__ offs,
                                                            int* __restrict__ eidx) {
    __shared__ int dcnt[256];
    __shared__ int sd[256];
    __shared__ int cur[256];
    int b = blockIdx.x, t = threadIdx.x;
    int base = bucket_offs[b], end = bucket_offs[b + 1];
    if (t < 256) dcnt[t] = 0;
    __syncthreads();
    for (int i = base + t; i < end; i += 1024)
        atomicAdd(&dcnt[pairs[i] & 255u], 1);
    __syncthreads();
    int v = 0;
    if (t < 256) { v = dcnt[t]; sd[t] = v; }
    __syncthreads();
    for (int off = 1; off < 256; off <<= 1) {
        int a = 0;
        if (t >= off && t < 256) a = sd[t - off];
        __syncthreads();
        if (t < 256) sd[t] += a;
        __syncthreads();
    }
    if (t < 256) {
        int excl = sd[t] - v;
        int node = b * 256 + t;
        if (node < N_NODES) offs[node] = base + excl;
        cur[t] = excl;
    }
    __syncthreads();
    for (int i = base + t; i < end; i += 1024) {
        unsigned r = pairs[i];
        int lp = atomicAdd(&cur[r & 255u], 1);
        eidx[base + lp] = (int)(r >> 8);
    }
}

// ---------------- fused aggregation + GEMM2 (R11 verbatim: best measured 69.3 us) ----------------
// De-fusing is a dead end (measured): split agg ~47 us + best-case epilogue
// ~22 us + launch >= the fused 69.3. The fused NPW=2 epilogue costs ~22 us of
// LDS return BW; scalar-V/readlane standalone variants lost to the register
// allocator twice (VGPR pinned 84/52, V loads sunk into loop). KEEP FUSED.

__global__ __launch_bounds__(1024) void agg_gemm_kernel(const unsigned short* __restrict__ hb,
                                                        const float* __restrict__ norm,
                                                        const float* __restrict__ V,
                                                        const int* __restrict__ offs,
                                                        const int* __restrict__ eidx,
                                                        float* __restrict__ out) {
    __shared__ float VL[HIDDEN * 68];      // 34,816 B
    __shared__ float pls[16][NPW][64];     // 8 KB
    int t = threadIdx.x;
    {
        const float4* V4 = (const float4*)V;
#pragma unroll
        for (int k = 0; k < 2; ++k) {
            int i4 = t + 1024 * k;
            float4 v = V4[i4];
            int el = i4 << 2;
            *(float4*)&VL[(el >> 6) * 68 + (el & 63)] = v;
        }
    }
    __syncthreads();

    int wave = t >> 6, lane = t & 63;
    int half = lane >> 5;      // which edge of the pair this lane serves
    int l32 = lane & 31;       // rank-pair index: ranks {2*l32, 2*l32+1}
    int nb = (blockIdx.x * 16 + wave) * NPW;   // first node of this wave
    const unsigned* hb2 = (const unsigned*)hb; // hb2[s*32 + l32] = packed ranks {2*l32, 2*l32+1}

#pragma unroll
    for (int i = 0; i < NPW; ++i) {
        int node = nb + i;
        int beg = offs[node], end = offs[node + 1];

        float plo = 1.0f, phi = 1.0f;
        for (int c = beg; c < end; c += 64) {
            int n = min(64, end - c);
            int sidx = (c + lane < end) ? eidx[c + lane] : 0;
            int j = 0;
            // 8 loads in flight = 16 edges
            for (; j + 16 <= n; j += 16) {
                int s0 = __shfl(sidx, j + 0  + half);
                int s1 = __shfl(sidx, j + 2  + half);
                int s2 = __shfl(sidx, j + 4  + half);
                int s3 = __shfl(sidx, j + 6  + half);
                int s4 = __shfl(sidx, j + 8  + half);
                int s5 = __shfl(sidx, j + 10 + half);
                int s6 = __shfl(sidx, j + 12 + half);
                int s7 = __shfl(sidx, j + 14 + half);
                unsigned u0 = hb2[(s0 << 5) | l32];
                unsigned u1 = hb2[(s1 << 5) | l32];
                unsigned u2 = hb2[(s2 << 5) | l32];
                unsigned u3 = hb2[(s3 << 5) | l32];
                unsigned u4 = hb2[(s4 << 5) | l32];
                unsigned u5 = hb2[(s5 << 5) | l32];
                unsigned u6 = hb2[(s6 << 5) | l32];
                unsigned u7 = hb2[(s7 << 5) | l32];
                plo *= ((bfu_lo(u0) * bfu_lo(u1)) * (bfu_lo(u2) * bfu_lo(u3))) *
                       ((bfu_lo(u4) * bfu_lo(u5)) * (bfu_lo(u6) * bfu_lo(u7)));
                phi *= ((bfu_hi(u0) * bfu_hi(u1)) * (bfu_hi(u2) * bfu_hi(u3))) *
                       ((bfu_hi(u4) * bfu_hi(u5)) * (bfu_hi(u6) * bfu_hi(u7)));
            }
            // 4 loads = 8 edges
            for (; j + 8 <= n; j += 8) {
                int s0 = __shfl(sidx, j + 0 + half);
                int s1 = __shfl(sidx, j + 2 + half);
                int s2 = __shfl(sidx, j + 4 + half);
                int s3 = __shfl(sidx, j + 6 + half);
                unsigned u0 = hb2[(s0 << 5) | l32];
                unsigned u1 = hb2[(s1 << 5) | l32];
                unsigned u2 = hb2[(s2 << 5) | l32];
                unsigned u3 = hb2[(s3 << 5) | l32];
                plo *= (bfu_lo(u0) * bfu_lo(u1)) * (bfu_lo(u2) * bfu_lo(u3));
                phi *= (bfu_hi(u0) * bfu_hi(u1)) * (bfu_hi(u2) * bfu_hi(u3));
            }
            // pair tail (2 edges / iter; odd edge masked to identity on upper half)
            for (; j < n; j += 2) {
                int jj = j + half;                 // jj <= n <= 64; lane n has sidx=0 -> safe addr
                int s = __shfl(sidx, jj);
                unsigned u = hb2[(s << 5) | l32];
                float alo = bfu_lo(u), ahi = bfu_hi(u);
                if (jj >= n) { alo = 1.0f; ahi = 1.0f; }
                plo *= alo;
                phi *= ahi;
            }
        }
        // merge edge-parity halves: lane l and lane l^32 hold the same rank pair
        plo *= __shfl_xor(plo, 32);
        phi *= __shfl_xor(phi, 32);

        if (lane < 32) {
            float nrm = norm[node];
            float2 o;
            o.x = plo * nrm;
            o.y = phi * nrm;
            *(float2*)&pls[wave][i][l32 * 2] = o;
        }
        // wave-private slab: no barrier needed (same-wave DS ordering via lgkmcnt)
    }

    // epilogue: each V fragment read once serves NPW=2 nodes (broadcast p reads
    // are same-address across the wave -> ~free).
    const float4* rA = (const float4*)&VL[lane * 68];
    const float4* rB = (const float4*)&VL[(lane + 64) * 68];
    const float4* p0 = (const float4*)pls[wave][0];
    const float4* p1 = (const float4*)pls[wave][1];
    float aA0 = 0.f, aB0 = 0.f, aA1 = 0.f, aB1 = 0.f;
#pragma unroll
    for (int q = 0; q < 16; ++q) {
        float4 va = rA[q];
        float4 vb = rB[q];
        float4 pp;
        pp = p0[q];   // broadcast read
        aA0 = fmaf(pp.x, va.x, fmaf(pp.y, va.y, fmaf(pp.z, va.z, fmaf(pp.w, va.w, aA0))));
        aB0 = fmaf(pp.x, vb.x, fmaf(pp.y, vb.y, fmaf(pp.z, vb.z, fmaf(pp.w, vb.w, aB0))));
        pp = p1[q];
        aA1 = fmaf(pp.x, va.x, fmaf(pp.y, va.y, fmaf(pp.z, va.z, fmaf(pp.w, va.w, aA1))));
        aB1 = fmaf(pp.x, vb.x, fmaf(pp.y, vb.y, fmaf(pp.z, vb.z, fmaf(pp.w, vb.w, aB1))));
    }
    out[(nb + 0) * HIDDEN + lane]      = aA0;
    out[(nb + 0) * HIDDEN + 64 + lane] = aB0;
    out[(nb + 1) * HIDDEN + lane]      = aA1;
    out[(nb + 1) * HIDDEN + 64 + lane] = aB1;
}

// ---------------- launch ----------------

extern "C" void kernel_launch(void* const* d_in, const int* in_sizes, int n_in,
                              void* d_out, int out_size, void* d_ws, size_t ws_size,
                              hipStream_t stream) {
    const float* x    = (const float*)d_in[0];
    const float* norm = (const float*)d_in[1];
    const float* W    = (const float*)d_in[2];
    const float* V    = (const float*)d_in[3];
    const int*   src  = (const int*)d_in[4];
    const int*   dst  = (const int*)d_in[5];
    float* out = (float*)d_out;

    // workspace layout (ws): hb (bf16), offs, eidx, small bucket arrays
    unsigned short* hb = (unsigned short*)d_ws;              // N*RANK bf16 (12.8 MB)
    int*   offs        = (int*)(hb + (long)N_NODES * RANK);  // N+1
    int*   eidx        = offs + N_NODES + 1;                 // E
    int*   bhist       = eidx + N_EDGES;                     // NBUCK
    int*   bucket_offs = bhist + NBUCK;                      // NBUCK+1
    int*   bucket_cur  = bucket_offs + NBUCK + 1;            // NBUCK

    // scratch inside d_out (dead until agg_gemm writes out):
    unsigned* pairs    = (unsigned*)d_out;                   // E uint32 (6.4 MB)
    int*     blockhist = (int*)d_out + 2097152;              // at +8 MB: C_BLOCKS*NBUCK ints (1.6 MB)

    hipMemsetAsync(bhist, 0, NBUCK * sizeof(int), stream);
    gemm1_hist_kernel<<<GEMM1_BLOCKS + C_BLOCKS, 256, 0, stream>>>(x, W, hb, dst, bhist, blockhist);
    bucket_scan_kernel<<<1, 512, 0, stream>>>(bhist, bucket_offs, bucket_cur, offs);
    binscatter_kernel<<<S_BLOCKS, 1024, 0, stream>>>(src, dst, blockhist, bucket_cur, pairs);
    bucket_build_kernel<<<NBUCK, 1024, 0, stream>>>(pairs, bucket_offs, offs, eidx);
    agg_gemm_kernel<<<AGG_BLOCKS, 1024, 0, stream>>>(hb, norm, V, offs, eidx, out);
}